// Round 8
// baseline (83.627 us; speedup 1.0000x reference)
//
#include <hip/hip_runtime.h>
#include <hip/hip_bf16.h>
#include <float.h>

// x: [B=32][C=3][L=8192] f32, weight: [O=128][C=3][K=64] f32
// out[b][o] = -2 * max_t ( conv(b,o,t) - ||w_o||^2/2 - ||win_{b,t}||^2/2 ), t in [0, 8129)
// *** MEASUREMENT PROBE ROUND: R4 (72.2us) kernel with the chunk pipeline
// *** repeated REPEAT times (idempotent max-accumulation) so shapeconv_main
// *** surfaces above the 40us harness fills in rocprof top-5 and we finally
// *** get real MfmaUtil/VALUBusy/Occupancy/VGPR/WRITE for the steady loop.
#define BB 32
#define LL 8192
#define OO 128
#define KK 64
#define WW (LL - KK + 1)   // 8129
#define NCH 3              // t-chunks of 256 per block
#define GX 11              // 11*3*256 = 8448 >= 8129; 704 blocks, 3 blocks/CU
#define REPEAT 2           // probe: x2 work, identical results

typedef __attribute__((ext_vector_type(8))) short short8;
typedef __attribute__((ext_vector_type(4))) float f32x4;

union AB { int4 i4; int i[4]; short8 v; };

static __device__ __forceinline__ unsigned int pkbf(float a, float b) {
    union { __hip_bfloat162 h; unsigned int u; } cv;
    cv.h = __float22bfloat162_rn(make_float2(a, b));   // lo = a, hi = b -> v_cvt_pk_bf16_f32
    return cv.u;
}

// ---- T14 stage split: issue loads early, pack+store late ----
// 80 threads each own 4 consecutive t: 3 channel float4 loads (single x read).
static __device__ __forceinline__ void stage_load(const float* __restrict__ x, int b, int T0,
                                                  int tid, float4* v) {
    v[0] = make_float4(0.f, 0.f, 0.f, 0.f);
    v[1] = v[0];
    v[2] = v[0];
    if (tid < 80) {
        int l = T0 + 4 * tid;
        if (l < LL) {
            const float* p = x + (size_t)b * 3 * LL + l;
            v[0] = *(const float4*)(p);
            v[1] = *(const float4*)(p + LL);
            v[2] = *(const float4*)(p + 2 * LL);
        }
    }
}

// pack bf16 tile (3x320) + sq float4 + P8 partials (pair shfl, no barrier)
static __device__ __forceinline__ void stage_store(int tid, const float4* v,
                                                   unsigned short* xl, float* sql, float* Pl) {
    if (tid >= 80) return;
    #pragma unroll
    for (int c = 0; c < 3; ++c) {
        uint2 pk;
        pk.x = pkbf(v[c].x, v[c].y);
        pk.y = pkbf(v[c].z, v[c].w);
        *(uint2*)(xl + c * 320 + tid * 4) = pk;
    }
    float4 sq4;
    sq4.x = fmaf(v[2].x, v[2].x, fmaf(v[1].x, v[1].x, v[0].x * v[0].x));
    sq4.y = fmaf(v[2].y, v[2].y, fmaf(v[1].y, v[1].y, v[0].y * v[0].y));
    sq4.z = fmaf(v[2].z, v[2].z, fmaf(v[1].z, v[1].z, v[0].z * v[0].z));
    sq4.w = fmaf(v[2].w, v[2].w, fmaf(v[1].w, v[1].w, v[0].w * v[0].w));
    *(float4*)(sql + tid * 4) = sq4;
    float s4 = (sq4.x + sq4.y) + (sq4.z + sq4.w);
    float s8 = s4 + __shfl_xor(s4, 1, 64);           // pairs (2i,2i+1), in-wave
    if ((tid & 1) == 0) Pl[tid >> 1] = s8;
}

// ---- main: grid (11 tcx, 2 ob, 32 b) = 704 blocks, 4 waves, <=3 chunks ----
__global__ __launch_bounds__(256, 3) void shapeconv_main(const float* __restrict__ x,
                                                         const float* __restrict__ w,
                                                         float* __restrict__ partial) {
    __shared__ __align__(16) unsigned short w_lds[64 * 192];     // 24576 B swizzled
    __shared__ __align__(16) unsigned short x_lds[2][3 * 320];   // 2x1920 B
    __shared__ __align__(16) float sq_lds[2][320];
    __shared__ __align__(16) float P_lds[2][40];
    __shared__ float wnp[4][64];                                 // ||w||^2 partials
    __shared__ float mred[64];

    const int tcx = blockIdx.x;
    const int ob = blockIdx.y;
    const int b  = blockIdx.z;
    const int tid = threadIdx.x;
    const int wv = tid >> 6;
    const int lane = tid & 63;
    const int wo = wv & 1, wt = wv >> 1;
    const int n  = lane & 15;
    const int qp = lane >> 4;
    const int Tb = tcx * (NCH * 256);
    const int rem = (WW - Tb + 255) >> 8;
    const int nch_eff = rem < NCH ? rem : NCH;       // skip dead tail chunk (tcx=10)

    // chunk-0 x loads issue first; latency hides under W conversion
    float4 sv[3];
    stage_load(x, b, Tb, tid, sv);

    // fused W prep: 6 swizzle-chunks/thread via v_cvt_pk_bf16_f32
    {
        const int o2 = tid & 63;
        const int row = tid >> 6;
        const float* wb = w + ((size_t)(ob * 64 + o2)) * 192;
        float wsq = 0.f;
        #pragma unroll
        for (int i = 0; i < 6; ++i) {
            int g = tid + 256 * i;                 // chunk = ((ks*4+qq)*64 + o2)
            int ksqp = g >> 6;
            int ks = ksqp >> 2, qq = ksqp & 3;
            int c = ks >> 1, h = ks & 1;
            const float4* p = (const float4*)(wb + c * 64 + h * 32 + qq * 8);
            float4 v0 = p[0], v1 = p[1];
            int4 pk;
            pk.x = (int)pkbf(v0.x, v0.y);
            pk.y = (int)pkbf(v0.z, v0.w);
            pk.z = (int)pkbf(v1.x, v1.y);
            pk.w = (int)pkbf(v1.z, v1.w);
            ((int4*)w_lds)[g] = pk;
            wsq = fmaf(v0.x, v0.x, wsq); wsq = fmaf(v0.y, v0.y, wsq);
            wsq = fmaf(v0.z, v0.z, wsq); wsq = fmaf(v0.w, v0.w, wsq);
            wsq = fmaf(v1.x, v1.x, wsq); wsq = fmaf(v1.y, v1.y, wsq);
            wsq = fmaf(v1.z, v1.z, wsq); wsq = fmaf(v1.w, v1.w, wsq);
        }
        wnp[row][o2] = wsq;
    }

    stage_store(tid, sv, x_lds[0], sq_lds[0], P_lds[0]);
    __syncthreads();   // B1(0): w_lds + wnp + chunk-0 staging visible

    float nw[2][4];
    #pragma unroll
    for (int ot = 0; ot < 2; ++ot)
        #pragma unroll
        for (int rg = 0; rg < 4; ++rg) {
            int o = 32 * wo + 16 * ot + 4 * qp + rg;
            nw[ot][rg] = 0.5f * ((wnp[0][o] + wnp[1][o]) + (wnp[2][o] + wnp[3][o]));
        }

    float m2[2][4];
    #pragma unroll
    for (int ot = 0; ot < 2; ++ot)
        #pragma unroll
        for (int rg = 0; rg < 4; ++rg) m2[ot][rg] = -FLT_MAX;

    for (int rep = 0; rep < REPEAT; ++rep) {
        if (rep) {
            // re-stage chunk 0 (identical data); barriers protect WAR on buf0
            __syncthreads();
            stage_load(x, b, Tb, tid, sv);
            stage_store(tid, sv, x_lds[0], sq_lds[0], P_lds[0]);
            __syncthreads();
        }

        for (int ci = 0; ci < nch_eff; ++ci) {
            const int bsel = ci & 1;
            const int T0 = Tb + ci * 256;
            const bool more = (ci + 1 < nch_eff);
            if (more) stage_load(x, b, T0 + 256, tid, sv);   // issue early (T14)

            // per-lane window half-norms
            float wl[8];
            {
                const float* sqp = sq_lds[bsel];
                const float* Pl  = P_lds[bsel];
                const int mi = 16 * wt + n;
                float S = 0.f;
                #pragma unroll
                for (int i = 0; i < 8; ++i) S += Pl[mi + i];
                #pragma unroll
                for (int r = 0; r < 8; ++r) {
                    wl[r] = (T0 + 8 * mi + r < WW) ? 0.5f * S : 1e30f;
                    if (r < 7) S += sqp[8 * mi + 64 + r] - sqp[8 * mi + r];
                }
            }

            // acc init with -(wn + win)
            f32x4 acc[2][8];
            #pragma unroll
            for (int ot = 0; ot < 2; ++ot)
                #pragma unroll
                for (int rg = 0; rg < 4; ++rg)
                    #pragma unroll
                    for (int r = 0; r < 8; ++r)
                        acc[ot][r][rg] = -nw[ot][rg] - wl[r];

            // K-loop: 6 ks x 8 r x 2 ot = 96 MFMAs/wave
            const char* xb = (const char*)x_lds[bsel];
            __builtin_amdgcn_s_setprio(1);
            #pragma unroll
            for (int ks = 0; ks < 6; ++ks) {
                int c = ks >> 1, h = ks & 1;
                int e0b = c * 640 + 256 * wt + 64 * h + 16 * (n + qp);
                int4 Ea = *(const int4*)(xb + e0b);
                int4 Eb = *(const int4*)(xb + e0b + 16);
                int D[8] = {Ea.x, Ea.y, Ea.z, Ea.w, Eb.x, Eb.y, Eb.z, Eb.w};
                AB a0, a1;
                const int4* wq = (const int4*)w_lds + (ks * 4 + qp) * 64 + 32 * wo;
                a0.i4 = wq[n];
                a1.i4 = wq[16 + n];
                #pragma unroll
                for (int r = 0; r < 8; ++r) {
                    AB bf;
                    int s = r >> 1;
                    if ((r & 1) == 0) {
                        bf.i[0] = D[s]; bf.i[1] = D[s + 1]; bf.i[2] = D[s + 2]; bf.i[3] = D[s + 3];
                    } else {
                        #pragma unroll
                        for (int d = 0; d < 4; ++d)
                            bf.i[d] = (int)__builtin_amdgcn_alignbit((unsigned)D[s + d + 1],
                                                                     (unsigned)D[s + d], 16);
                    }
                    acc[0][r] = __builtin_amdgcn_mfma_f32_16x16x32_bf16(a0.v, bf.v, acc[0][r], 0, 0, 0);
                    acc[1][r] = __builtin_amdgcn_mfma_f32_16x16x32_bf16(a1.v, bf.v, acc[1][r], 0, 0, 0);
                }
            }
            __builtin_amdgcn_s_setprio(0);

            // per-chunk register max
            #pragma unroll
            for (int ot = 0; ot < 2; ++ot)
                #pragma unroll
                for (int rg = 0; rg < 4; ++rg) {
                    float mm = m2[ot][rg];
                    #pragma unroll
                    for (int r = 0; r < 8; ++r) mm = fmaxf(mm, acc[ot][r][rg]);
                    m2[ot][rg] = mm;
                }

            if (more) {
                stage_store(tid, sv, x_lds[1 - bsel], sq_lds[1 - bsel], P_lds[1 - bsel]);
                __syncthreads();   // staging visible + WAR protection
            }
        }
    }

    // cross-lane max over n -> wt-pair combine -> dump
    #pragma unroll
    for (int s = 1; s <= 8; s <<= 1)
        #pragma unroll
        for (int ot = 0; ot < 2; ++ot)
            #pragma unroll
            for (int rg = 0; rg < 4; ++rg)
                m2[ot][rg] = fmaxf(m2[ot][rg], __shfl_xor(m2[ot][rg], s, 64));

    if (wt == 1 && n == 0) {
        #pragma unroll
        for (int ot = 0; ot < 2; ++ot)
            #pragma unroll
            for (int rg = 0; rg < 4; ++rg)
                mred[32 * wo + 16 * ot + 4 * qp + rg] = m2[ot][rg];
    }
    __syncthreads();
    if (wt == 0 && n == 0) {
        #pragma unroll
        for (int ot = 0; ot < 2; ++ot)
            #pragma unroll
            for (int rg = 0; rg < 4; ++rg) {
                int oi = 32 * wo + 16 * ot + 4 * qp + rg;
                float v = fmaxf(m2[ot][rg], mred[oi]);
                partial[((size_t)(b * GX + tcx) * 2 + ob) * 64 + oi] = v;
            }
    }
}

// max over the 11 tcx chunks, scale by -2
__global__ __launch_bounds__(256) void reduce_kernel(const float* __restrict__ partial,
                                                     float* __restrict__ out) {
    int idx = blockIdx.x * 256 + threadIdx.x;   // 4096 = 32*128
    int b = idx >> 7, o = idx & 127;
    const float* pp = partial + ((size_t)b * GX * 2 + (o >> 6)) * 64 + (o & 63);
    float mx = -FLT_MAX;
    #pragma unroll
    for (int t = 0; t < GX; ++t) mx = fmaxf(mx, pp[(size_t)t * 128]);
    out[idx] = -2.f * mx;
}

extern "C" void kernel_launch(void* const* d_in, const int* in_sizes, int n_in,
                              void* d_out, int out_size, void* d_ws, size_t ws_size,
                              hipStream_t stream) {
    const float* x = (const float*)d_in[0];   // [32][3][8192]
    const float* w = (const float*)d_in[1];   // [128][3][64]
    float* out = (float*)d_out;               // [32][128]

    // ws: partial f32 [32][11][2][64]
    float* partial = (float*)d_ws;

    dim3 grid(GX, 2, BB);                     // 704 blocks
    shapeconv_main<<<grid, 256, 0, stream>>>(x, w, partial);
    reduce_kernel<<<16, 256, 0, stream>>>(partial, out);
}

// Round 9
// 72.096 us; speedup vs baseline: 1.1599x; 1.1599x over previous
//
#include <hip/hip_runtime.h>
#include <hip/hip_bf16.h>
#include <float.h>

// x: [B=32][C=3][L=8192] f32, weight: [O=128][C=3][K=64] f32
// out[b][o] = -2 * max_t ( conv(b,o,t) - ||w_o||^2/2 - ||win_{b,t}||^2/2 ), t in [0, 8129)
#define BB 32
#define LL 8192
#define OO 128
#define KK 64
#define WW (LL - KK + 1)   // 8129
#define NCH 3              // t-chunks of 256 per block
#define GX 11              // 11*3*256 = 8448 >= 8129; 704 blocks, 3 blocks/CU

typedef __attribute__((ext_vector_type(8))) short short8;
typedef __attribute__((ext_vector_type(4))) float f32x4;

union AB { int4 i4; int i[4]; short8 v; };

static __device__ __forceinline__ unsigned int pkbf(float a, float b) {
    union { __hip_bfloat162 h; unsigned int u; } cv;
    cv.h = __float22bfloat162_rn(make_float2(a, b));   // lo = a, hi = b -> v_cvt_pk_bf16_f32
    return cv.u;
}

// ---- T14 stage split: issue loads early, pack+store late ----
// 80 threads each own 4 consecutive t: 3 channel float4 loads (single x read).
static __device__ __forceinline__ void stage_load(const float* __restrict__ x, int b, int T0,
                                                  int tid, float4* v) {
    v[0] = make_float4(0.f, 0.f, 0.f, 0.f);
    v[1] = v[0];
    v[2] = v[0];
    if (tid < 80) {
        int l = T0 + 4 * tid;
        if (l < LL) {
            const float* p = x + (size_t)b * 3 * LL + l;
            v[0] = *(const float4*)(p);
            v[1] = *(const float4*)(p + LL);
            v[2] = *(const float4*)(p + 2 * LL);
        }
    }
}

// pack bf16 tile (3x320) + sq float4 + P8 partials (pair shfl, no barrier)
static __device__ __forceinline__ void stage_store(int tid, const float4* v,
                                                   unsigned short* xl, float* sql, float* Pl) {
    if (tid >= 80) return;
    #pragma unroll
    for (int c = 0; c < 3; ++c) {
        uint2 pk;
        pk.x = pkbf(v[c].x, v[c].y);
        pk.y = pkbf(v[c].z, v[c].w);
        *(uint2*)(xl + c * 320 + tid * 4) = pk;
    }
    float4 sq4;
    sq4.x = fmaf(v[2].x, v[2].x, fmaf(v[1].x, v[1].x, v[0].x * v[0].x));
    sq4.y = fmaf(v[2].y, v[2].y, fmaf(v[1].y, v[1].y, v[0].y * v[0].y));
    sq4.z = fmaf(v[2].z, v[2].z, fmaf(v[1].z, v[1].z, v[0].z * v[0].z));
    sq4.w = fmaf(v[2].w, v[2].w, fmaf(v[1].w, v[1].w, v[0].w * v[0].w));
    *(float4*)(sql + tid * 4) = sq4;
    float s4 = (sq4.x + sq4.y) + (sq4.z + sq4.w);
    float s8 = s4 + __shfl_xor(s4, 1, 64);           // pairs (2i,2i+1), in-wave
    if ((tid & 1) == 0) Pl[tid >> 1] = s8;
}

// ---- main: grid (11 tcx, 2 ob, 32 b) = 704 blocks, 4 waves, <=3 chunks ----
// Wave (wo=wv&1, wt=wv>>1): o in [64ob+32wo, +32), t = T0 + 128wt + r + 8n.
// One barrier per chunk; fused W-prep; fused tail via atomicMin (out pre-memset).
__global__ __launch_bounds__(256, 3) void shapeconv_main(const float* __restrict__ x,
                                                         const float* __restrict__ w,
                                                         float* __restrict__ out) {
    __shared__ __align__(16) unsigned short w_lds[64 * 192];     // 24576 B swizzled
    __shared__ __align__(16) unsigned short x_lds[2][3 * 320];   // 2x1920 B
    __shared__ __align__(16) float sq_lds[2][320];
    __shared__ __align__(16) float P_lds[2][40];
    __shared__ float wnp[4][64];                                 // ||w||^2 partials
    __shared__ float mred[64];

    const int tcx = blockIdx.x;
    const int ob = blockIdx.y;
    const int b  = blockIdx.z;
    const int tid = threadIdx.x;
    const int wv = tid >> 6;
    const int lane = tid & 63;
    const int wo = wv & 1, wt = wv >> 1;
    const int n  = lane & 15;
    const int qp = lane >> 4;
    const int Tb = tcx * (NCH * 256);
    const int rem = (WW - Tb + 255) >> 8;
    const int nch_eff = rem < NCH ? rem : NCH;       // skip dead tail chunk (tcx=10)

    // chunk-0 x loads issue first; latency hides under W conversion
    float4 sv[3];
    stage_load(x, b, Tb, tid, sv);

    // fused W prep: 6 swizzle-chunks/thread via v_cvt_pk_bf16_f32;
    // o2 = tid&63 constant per thread -> ||w||^2 partials per (row, o2).
    {
        const int o2 = tid & 63;
        const int row = tid >> 6;
        const float* wb = w + ((size_t)(ob * 64 + o2)) * 192;
        float wsq = 0.f;
        #pragma unroll
        for (int i = 0; i < 6; ++i) {
            int g = tid + 256 * i;                 // chunk = ((ks*4+qq)*64 + o2)
            int ksqp = g >> 6;
            int ks = ksqp >> 2, qq = ksqp & 3;
            int c = ks >> 1, h = ks & 1;
            const float4* p = (const float4*)(wb + c * 64 + h * 32 + qq * 8);
            float4 v0 = p[0], v1 = p[1];
            int4 pk;
            pk.x = (int)pkbf(v0.x, v0.y);
            pk.y = (int)pkbf(v0.z, v0.w);
            pk.z = (int)pkbf(v1.x, v1.y);
            pk.w = (int)pkbf(v1.z, v1.w);
            ((int4*)w_lds)[g] = pk;
            wsq = fmaf(v0.x, v0.x, wsq); wsq = fmaf(v0.y, v0.y, wsq);
            wsq = fmaf(v0.z, v0.z, wsq); wsq = fmaf(v0.w, v0.w, wsq);
            wsq = fmaf(v1.x, v1.x, wsq); wsq = fmaf(v1.y, v1.y, wsq);
            wsq = fmaf(v1.z, v1.z, wsq); wsq = fmaf(v1.w, v1.w, wsq);
        }
        wnp[row][o2] = wsq;
    }

    stage_store(tid, sv, x_lds[0], sq_lds[0], P_lds[0]);
    __syncthreads();   // B1(0): w_lds + wnp + chunk-0 staging visible

    // per-lane shapelet half-norms (folded into acc init)
    float nw[2][4];
    #pragma unroll
    for (int ot = 0; ot < 2; ++ot)
        #pragma unroll
        for (int rg = 0; rg < 4; ++rg) {
            int o = 32 * wo + 16 * ot + 4 * qp + rg;
            nw[ot][rg] = 0.5f * ((wnp[0][o] + wnp[1][o]) + (wnp[2][o] + wnp[3][o]));
        }

    float m2[2][4];
    #pragma unroll
    for (int ot = 0; ot < 2; ++ot)
        #pragma unroll
        for (int rg = 0; rg < 4; ++rg) m2[ot][rg] = -FLT_MAX;

    for (int ci = 0; ci < nch_eff; ++ci) {
        const int bsel = ci & 1;
        const int T0 = Tb + ci * 256;
        const bool more = (ci + 1 < nch_eff);
        if (more) stage_load(x, b, T0 + 256, tid, sv);   // issue early (T14)

        // per-lane window half-norms: base = sum of 8 P partials + 7 incremental
        // updates. Lane owns t = T0 + 8*mi + r, mi = 16wt + n (qp lanes broadcast).
        float wl[8];
        {
            const float* sqp = sq_lds[bsel];
            const float* Pl  = P_lds[bsel];
            const int mi = 16 * wt + n;
            float S = 0.f;
            #pragma unroll
            for (int i = 0; i < 8; ++i) S += Pl[mi + i];
            #pragma unroll
            for (int r = 0; r < 8; ++r) {
                wl[r] = (T0 + 8 * mi + r < WW) ? 0.5f * S : 1e30f;
                if (r < 7) S += sqp[8 * mi + 64 + r] - sqp[8 * mi + r];
            }
        }

        // acc init with -(wn + win)
        f32x4 acc[2][8];
        #pragma unroll
        for (int ot = 0; ot < 2; ++ot)
            #pragma unroll
            for (int rg = 0; rg < 4; ++rg)
                #pragma unroll
                for (int r = 0; r < 8; ++r)
                    acc[ot][r][rg] = -nw[ot][rg] - wl[r];

        // K-loop: 6 ks x 8 r x 2 ot = 96 MFMAs/wave
        const char* xb = (const char*)x_lds[bsel];
        __builtin_amdgcn_s_setprio(1);
        #pragma unroll
        for (int ks = 0; ks < 6; ++ks) {
            int c = ks >> 1, h = ks & 1;
            int e0b = c * 640 + 256 * wt + 64 * h + 16 * (n + qp);
            int4 Ea = *(const int4*)(xb + e0b);
            int4 Eb = *(const int4*)(xb + e0b + 16);
            int D[8] = {Ea.x, Ea.y, Ea.z, Ea.w, Eb.x, Eb.y, Eb.z, Eb.w};
            AB a0, a1;
            const int4* wq = (const int4*)w_lds + (ks * 4 + qp) * 64 + 32 * wo;
            a0.i4 = wq[n];
            a1.i4 = wq[16 + n];
            #pragma unroll
            for (int r = 0; r < 8; ++r) {
                AB bf;
                int s = r >> 1;
                if ((r & 1) == 0) {
                    bf.i[0] = D[s]; bf.i[1] = D[s + 1]; bf.i[2] = D[s + 2]; bf.i[3] = D[s + 3];
                } else {
                    #pragma unroll
                    for (int d = 0; d < 4; ++d)
                        bf.i[d] = (int)__builtin_amdgcn_alignbit((unsigned)D[s + d + 1],
                                                                 (unsigned)D[s + d], 16);
                }
                acc[0][r] = __builtin_amdgcn_mfma_f32_16x16x32_bf16(a0.v, bf.v, acc[0][r], 0, 0, 0);
                acc[1][r] = __builtin_amdgcn_mfma_f32_16x16x32_bf16(a1.v, bf.v, acc[1][r], 0, 0, 0);
            }
        }
        __builtin_amdgcn_s_setprio(0);

        // per-chunk register max
        #pragma unroll
        for (int ot = 0; ot < 2; ++ot)
            #pragma unroll
            for (int rg = 0; rg < 4; ++rg) {
                float mm = m2[ot][rg];
                #pragma unroll
                for (int r = 0; r < 8; ++r) mm = fmaxf(mm, acc[ot][r][rg]);
                m2[ot][rg] = mm;
            }

        if (more) {
            // write late: the global loads issued before the K-loop retired long ago
            stage_store(tid, sv, x_lds[1 - bsel], sq_lds[1 - bsel], P_lds[1 - bsel]);
            __syncthreads();   // B1(ci+1): staging visible + WAR protection
        }
    }

    // cross-lane max over n -> wt-pair combine -> fused global reduce (atomicMin)
    #pragma unroll
    for (int s = 1; s <= 8; s <<= 1)
        #pragma unroll
        for (int ot = 0; ot < 2; ++ot)
            #pragma unroll
            for (int rg = 0; rg < 4; ++rg)
                m2[ot][rg] = fmaxf(m2[ot][rg], __shfl_xor(m2[ot][rg], s, 64));

    if (wt == 1 && n == 0) {
        #pragma unroll
        for (int ot = 0; ot < 2; ++ot)
            #pragma unroll
            for (int rg = 0; rg < 4; ++rg)
                mred[32 * wo + 16 * ot + 4 * qp + rg] = m2[ot][rg];
    }
    __syncthreads();
    if (wt == 0 && n == 0) {
        #pragma unroll
        for (int ot = 0; ot < 2; ++ot)
            #pragma unroll
            for (int rg = 0; rg < 4; ++rg) {
                int oi = 32 * wo + 16 * ot + 4 * qp + rg;
                float v = fmaxf(m2[ot][rg], mred[oi]);
                // -2*v is a squared distance (>= -bf16 noise): int ordering on
                // float bits is correct for non-negatives; out pre-set to
                // 0x7F7F7F7F = 3.39e38 by hipMemsetAsync. 11 atomics/address.
                atomicMin((int*)(out + (size_t)b * OO + ob * 64 + oi),
                          __float_as_int(-2.0f * v));
            }
    }
}

extern "C" void kernel_launch(void* const* d_in, const int* in_sizes, int n_in,
                              void* d_out, int out_size, void* d_ws, size_t ws_size,
                              hipStream_t stream) {
    const float* x = (const float*)d_in[0];   // [32][3][8192]
    const float* w = (const float*)d_in[1];   // [128][3][64]
    float* out = (float*)d_out;               // [32][128]

    // out := 0x7F7F7F7F per byte = 3.39e38f ("+inf" for atomicMin-as-int).
    // Memset nodes are graph-capture-legal (the harness's own fills are memsets).
    hipMemsetAsync(out, 0x7F, (size_t)BB * OO * sizeof(float), stream);

    dim3 grid(GX, 2, BB);                     // 704 blocks, fused tail
    shapeconv_main<<<grid, 256, 0, stream>>>(x, w, out);
}